// Round 1
// baseline (1375.226 us; speedup 1.0000x reference)
//
#include <hip/hip_runtime.h>
#include <hip/hip_bf16.h>

// BinaryLinear: C[M,N] = (x[M,K] @ sign(W)[N,K]^T) * scale + bias
// M=8192 K=4096 N=16384, fp32 in/out. Strategy: binarize W to +-1 bf16,
// round x to bf16, run bf16 MFMA GEMM (fp32 accum). 1.1 TFLOP -> compute-bound.

typedef __attribute__((ext_vector_type(4))) float f32x4;
typedef __attribute__((ext_vector_type(8))) short s16x8;
typedef __attribute__((ext_vector_type(4))) unsigned int u32x4;

#define BM 128
#define BN 128
#define BKK 64

#define AS1(p) ((const __attribute__((address_space(1))) void*)(p))
#define AS3(p) ((__attribute__((address_space(3))) void*)(p))

__device__ __forceinline__ unsigned short f2bf(float f) {
  // round-to-nearest-even fp32 -> bf16 (inputs are finite)
  unsigned u = __float_as_uint(f);
  u += 0x7FFFu + ((u >> 16) & 1u);
  return (unsigned short)(u >> 16);
}

__global__ void __launch_bounds__(256) cvt_f32_bf16(const float* __restrict__ in,
                                                    unsigned short* __restrict__ out,
                                                    int n8) {
  int i = blockIdx.x * 256 + threadIdx.x;
  const int stride = gridDim.x * 256;
  for (; i < n8; i += stride) {
    const f32x4* p = (const f32x4*)in + (size_t)i * 2;
    f32x4 v0 = p[0], v1 = p[1];
    s16x8 o;
    o[0] = (short)f2bf(v0[0]); o[1] = (short)f2bf(v0[1]);
    o[2] = (short)f2bf(v0[2]); o[3] = (short)f2bf(v0[3]);
    o[4] = (short)f2bf(v1[0]); o[5] = (short)f2bf(v1[1]);
    o[6] = (short)f2bf(v1[2]); o[7] = (short)f2bf(v1[3]);
    *(s16x8*)(out + (size_t)i * 8) = o;
  }
}

__global__ void __launch_bounds__(256) bin_f32_bf16(const unsigned int* __restrict__ in,
                                                    unsigned short* __restrict__ out,
                                                    int n8) {
  int i = blockIdx.x * 256 + threadIdx.x;
  const int stride = gridDim.x * 256;
  for (; i < n8; i += stride) {
    const u32x4* p = (const u32x4*)in + (size_t)i * 2;
    u32x4 v0 = p[0], v1 = p[1];
    s16x8 o;  // bf16 +-1.0 from fp32 sign bit (sign(0)=+1: +0.0 -> +1)
    o[0] = (short)(0x3F80u | ((v0[0] >> 16) & 0x8000u));
    o[1] = (short)(0x3F80u | ((v0[1] >> 16) & 0x8000u));
    o[2] = (short)(0x3F80u | ((v0[2] >> 16) & 0x8000u));
    o[3] = (short)(0x3F80u | ((v0[3] >> 16) & 0x8000u));
    o[4] = (short)(0x3F80u | ((v1[0] >> 16) & 0x8000u));
    o[5] = (short)(0x3F80u | ((v1[1] >> 16) & 0x8000u));
    o[6] = (short)(0x3F80u | ((v1[2] >> 16) & 0x8000u));
    o[7] = (short)(0x3F80u | ((v1[3] >> 16) & 0x8000u));
    *(s16x8*)(out + (size_t)i * 8) = o;
  }
}

// 128x128 tile, BK=64, 4 waves (2x2), wave tile 64x64 = 4x4 frags of 16x16x32.
// LDS layout: 16B chunks, chunk(row,kc) at linear slot row*8 + (kc ^ (row&7)).
// Swizzle breaks the 16-way bank conflict of row-major [128][64]bf16 (128B rows).
// bf16 path: linear global_load_lds dest + inverse-swizzled global source.
// fp32 path: linear global source + swizzled ds_write (same final layout).
template <bool ABF, bool BBF>
__global__ void __launch_bounds__(256, 2)
gemm_bin(const void* __restrict__ Ap, const void* __restrict__ Bp,
         const float* __restrict__ scale, const float* __restrict__ bias,
         float* __restrict__ C, const int M, const int N, const int K) {
  __shared__ unsigned short As[BM * BKK];
  __shared__ unsigned short Bs[BN * BKK];
  const int tid = threadIdx.x;
  const int lane = tid & 63;
  const int wv = tid >> 6;
  const int wm = wv >> 1, wn = wv & 1;
  const int bn = blockIdx.x, bm = blockIdx.y;
  const int lr = lane & 15, lk = lane >> 4;

  f32x4 acc[4][4] = {};

  const int rA0 = bm * BM;
  const int rB0 = bn * BN;

  for (int k0 = 0; k0 < K; k0 += BKK) {
    // ---- stage A tile (128 x 64 bf16) ----
    if constexpr (ABF) {
      const unsigned short* Ag = (const unsigned short*)Ap;
#pragma unroll
      for (int i = 0; i < 4; ++i) {
        const int cbase = i * 256 + wv * 64;  // wave-uniform LDS chunk base
        const int c = cbase + lane;
        const int row = c >> 3, kc = c & 7;
        const int kcs = kc ^ (row & 7);  // inverse-swizzle the SOURCE
        const unsigned short* src = Ag + (size_t)(rA0 + row) * K + (k0 + kcs * 8);
        __builtin_amdgcn_global_load_lds(AS1(src), AS3(&As[cbase * 8]), 16, 0, 0);
      }
    } else {
      const float* Ag = (const float*)Ap;
#pragma unroll
      for (int i = 0; i < 4; ++i) {
        const int c = i * 256 + tid;
        const int row = c >> 3, kc = c & 7;
        const f32x4* src = (const f32x4*)(Ag + (size_t)(rA0 + row) * K + (k0 + kc * 8));
        f32x4 v0 = src[0], v1 = src[1];
        s16x8 o;
        o[0] = (short)f2bf(v0[0]); o[1] = (short)f2bf(v0[1]);
        o[2] = (short)f2bf(v0[2]); o[3] = (short)f2bf(v0[3]);
        o[4] = (short)f2bf(v1[0]); o[5] = (short)f2bf(v1[1]);
        o[6] = (short)f2bf(v1[2]); o[7] = (short)f2bf(v1[3]);
        *(s16x8*)&As[(row * 8 + (kc ^ (row & 7))) * 8] = o;
      }
    }
    // ---- stage B tile (128 x 64 bf16, binarized weight rows) ----
    if constexpr (BBF) {
      const unsigned short* Bg = (const unsigned short*)Bp;
#pragma unroll
      for (int i = 0; i < 4; ++i) {
        const int cbase = i * 256 + wv * 64;
        const int c = cbase + lane;
        const int row = c >> 3, kc = c & 7;
        const int kcs = kc ^ (row & 7);
        const unsigned short* src = Bg + (size_t)(rB0 + row) * K + (k0 + kcs * 8);
        __builtin_amdgcn_global_load_lds(AS1(src), AS3(&Bs[cbase * 8]), 16, 0, 0);
      }
    } else {
      const unsigned int* Bg = (const unsigned int*)Bp;
#pragma unroll
      for (int i = 0; i < 4; ++i) {
        const int c = i * 256 + tid;
        const int row = c >> 3, kc = c & 7;
        const u32x4* src = (const u32x4*)(Bg + (size_t)(rB0 + row) * K + (k0 + kc * 8));
        u32x4 v0 = src[0], v1 = src[1];
        s16x8 o;
        o[0] = (short)(0x3F80u | ((v0[0] >> 16) & 0x8000u));
        o[1] = (short)(0x3F80u | ((v0[1] >> 16) & 0x8000u));
        o[2] = (short)(0x3F80u | ((v0[2] >> 16) & 0x8000u));
        o[3] = (short)(0x3F80u | ((v0[3] >> 16) & 0x8000u));
        o[4] = (short)(0x3F80u | ((v1[0] >> 16) & 0x8000u));
        o[5] = (short)(0x3F80u | ((v1[1] >> 16) & 0x8000u));
        o[6] = (short)(0x3F80u | ((v1[2] >> 16) & 0x8000u));
        o[7] = (short)(0x3F80u | ((v1[3] >> 16) & 0x8000u));
        *(s16x8*)&Bs[(row * 8 + (kc ^ (row & 7))) * 8] = o;
      }
    }
    __syncthreads();  // drains vmcnt (global_load_lds) + lgkmcnt (ds_write)

#pragma unroll
    for (int ks = 0; ks < 2; ++ks) {
      s16x8 a[4], b[4];
#pragma unroll
      for (int mi = 0; mi < 4; ++mi) {
        const int row = wm * 64 + mi * 16 + lr;
        const int kc = ks * 4 + lk;
        a[mi] = *(const s16x8*)&As[(row * 8 + (kc ^ (row & 7))) * 8];
      }
#pragma unroll
      for (int ni = 0; ni < 4; ++ni) {
        const int row = wn * 64 + ni * 16 + lr;
        const int kc = ks * 4 + lk;
        b[ni] = *(const s16x8*)&Bs[(row * 8 + (kc ^ (row & 7))) * 8];
      }
#pragma unroll
      for (int mi = 0; mi < 4; ++mi)
#pragma unroll
        for (int ni = 0; ni < 4; ++ni)
          acc[mi][ni] = __builtin_amdgcn_mfma_f32_16x16x32_bf16(a[mi], b[ni],
                                                               acc[mi][ni], 0, 0, 0);
    }
    __syncthreads();
  }

  // epilogue: C[m][n] = acc * scale + bias[n]
  // C/D layout (m89): col = lane&15, row = (lane>>4)*4 + reg
  const float s = scale[0];
  const int n0 = rB0 + wn * 64 + lr;
  const int m0 = rA0 + wm * 64 + lk * 4;
  float bv[4];
#pragma unroll
  for (int ni = 0; ni < 4; ++ni) bv[ni] = bias[n0 + ni * 16];
#pragma unroll
  for (int mi = 0; mi < 4; ++mi) {
#pragma unroll
    for (int r = 0; r < 4; ++r) {
      float* crow = C + (size_t)(m0 + mi * 16 + r) * N + n0;
#pragma unroll
      for (int ni = 0; ni < 4; ++ni)
        crow[ni * 16] = acc[mi][ni][r] * s + bv[ni];
    }
  }
}

extern "C" void kernel_launch(void* const* d_in, const int* in_sizes, int n_in,
                              void* d_out, int out_size, void* d_ws, size_t ws_size,
                              hipStream_t stream) {
  const float* x = (const float*)d_in[0];
  const float* w = (const float*)d_in[1];
  const float* scale = (const float*)d_in[2];
  const float* bias = (const float*)d_in[3];
  float* out = (float*)d_out;

  const int K = 4096;
  const int M = in_sizes[0] / K;  // 8192
  const int N = in_sizes[3];      // 16384

  const size_t needA = (size_t)M * K * sizeof(unsigned short);  // 64 MB
  const size_t needB = (size_t)N * K * sizeof(unsigned short);  // 128 MB

  dim3 grid(N / BN, M / BM), block(256);

  if (ws_size >= needA + needB) {
    unsigned short* xb = (unsigned short*)d_ws;
    unsigned short* wb = (unsigned short*)((char*)d_ws + needA);
    cvt_f32_bf16<<<2048, 256, 0, stream>>>(x, xb, (M * K) / 8);
    bin_f32_bf16<<<2048, 256, 0, stream>>>((const unsigned int*)w, wb, (N * K) / 8);
    gemm_bin<true, true><<<grid, block, 0, stream>>>(xb, wb, scale, bias, out, M, N, K);
  } else if (ws_size >= needB) {
    unsigned short* wb = (unsigned short*)d_ws;
    bin_f32_bf16<<<2048, 256, 0, stream>>>((const unsigned int*)w, wb, (N * K) / 8);
    gemm_bin<false, true><<<grid, block, 0, stream>>>(x, wb, scale, bias, out, M, N, K);
  } else if (ws_size >= needA) {
    unsigned short* xb = (unsigned short*)d_ws;
    cvt_f32_bf16<<<2048, 256, 0, stream>>>(x, xb, (M * K) / 8);
    gemm_bin<true, false><<<grid, block, 0, stream>>>(xb, w, scale, bias, out, M, N, K);
  } else {
    gemm_bin<false, false><<<grid, block, 0, stream>>>(x, w, scale, bias, out, M, N, K);
  }
}

// Round 2
// 1308.402 us; speedup vs baseline: 1.0511x; 1.0511x over previous
//
#include <hip/hip_runtime.h>
#include <hip/hip_bf16.h>

// BinaryLinear: C[M,N] = (x[M,K] @ sign(W)[N,K]^T) * scale + bias
// M=8192 K=4096 N=16384 fp32. Binarize W -> +-1 bf16, round x -> bf16,
// bf16 MFMA GEMM. Round 2: 256x256 8-wave 4-phase schedule, counted vmcnt,
// K-half LDS regions with bank-conflict-free swizzle, setprio, XCD swizzle.

typedef __attribute__((ext_vector_type(4))) float f32x4;
typedef __attribute__((ext_vector_type(8))) short s16x8;
typedef __attribute__((ext_vector_type(4))) unsigned int u32x4;

#define AS1(p) ((const __attribute__((address_space(1))) void*)(p))
#define AS3(p) ((__attribute__((address_space(3))) void*)(p))

__device__ __forceinline__ unsigned short f2bf(float f) {
  unsigned u = __float_as_uint(f);
  u += 0x7FFFu + ((u >> 16) & 1u);
  return (unsigned short)(u >> 16);
}

__global__ void __launch_bounds__(256) cvt_f32_bf16(const float* __restrict__ in,
                                                    unsigned short* __restrict__ out,
                                                    int n8) {
  int i = blockIdx.x * 256 + threadIdx.x;
  const int stride = gridDim.x * 256;
  for (; i < n8; i += stride) {
    const f32x4* p = (const f32x4*)in + (size_t)i * 2;
    f32x4 v0 = p[0], v1 = p[1];
    s16x8 o;
    o[0] = (short)f2bf(v0[0]); o[1] = (short)f2bf(v0[1]);
    o[2] = (short)f2bf(v0[2]); o[3] = (short)f2bf(v0[3]);
    o[4] = (short)f2bf(v1[0]); o[5] = (short)f2bf(v1[1]);
    o[6] = (short)f2bf(v1[2]); o[7] = (short)f2bf(v1[3]);
    *(s16x8*)(out + (size_t)i * 8) = o;
  }
}

__global__ void __launch_bounds__(256) bin_f32_bf16(const unsigned int* __restrict__ in,
                                                    unsigned short* __restrict__ out,
                                                    int n8) {
  int i = blockIdx.x * 256 + threadIdx.x;
  const int stride = gridDim.x * 256;
  for (; i < n8; i += stride) {
    const u32x4* p = (const u32x4*)in + (size_t)i * 2;
    u32x4 v0 = p[0], v1 = p[1];
    s16x8 o;  // bf16 +-1.0 from fp32 sign bit
    o[0] = (short)(0x3F80u | ((v0[0] >> 16) & 0x8000u));
    o[1] = (short)(0x3F80u | ((v0[1] >> 16) & 0x8000u));
    o[2] = (short)(0x3F80u | ((v0[2] >> 16) & 0x8000u));
    o[3] = (short)(0x3F80u | ((v0[3] >> 16) & 0x8000u));
    o[4] = (short)(0x3F80u | ((v1[0] >> 16) & 0x8000u));
    o[5] = (short)(0x3F80u | ((v1[1] >> 16) & 0x8000u));
    o[6] = (short)(0x3F80u | ((v1[2] >> 16) & 0x8000u));
    o[7] = (short)(0x3F80u | ((v1[3] >> 16) & 0x8000u));
    *(s16x8*)(out + (size_t)i * 8) = o;
  }
}

// ---------------------------------------------------------------------------
// 256x256 tile, BK=64, 512 threads = 8 waves (2M x 4N), wave tile 128x64.
// LDS (128 KiB): buf{0,1} x op{A,B} x Khalf{0,1} regions of 256 rows x 64 B.
//   byte = buf*65536 + op*32768 + h*16384 + row*64 + (kc ^ ((row>>1)&3))*16
// Stage: global_load_lds w=16, linear dest, inverse-swizzled source.
// 4 phases per K-tile: ph1 (ks0,mih0: 8 ds_reads), ph2 (ks0,mih1: 4),
// ph3 (ks1,mih0: 8), ph4 (ks1,mih1: 4); one half-region of tile t+1 staged
// per phase in order [A-K0, B-K0, A-K1, B-K1]; vmcnt(4) at ends of ph2/ph4
// retires exactly the halves read by the next two phases (never drain to 0).
// ---------------------------------------------------------------------------

#define WAITV4() asm volatile("s_waitcnt vmcnt(4)" ::: "memory")
#define WAITV0() asm volatile("s_waitcnt vmcnt(0)" ::: "memory")
#define LGK0()   asm volatile("s_waitcnt lgkmcnt(0)" ::: "memory")
#define BAR()    __builtin_amdgcn_s_barrier()
#define SCHED0() __builtin_amdgcn_sched_barrier(0)
#define PRIO(x)  __builtin_amdgcn_s_setprio(x)

#define LDA4(ks, mih)                                                          \
  do {                                                                         \
    _Pragma("unroll") for (int mi = 0; mi < 4; ++mi)                           \
        av[mi] = *(const s16x8*)((const char*)lds + bufR + rdA +               \
                                 (ks) * 16384 + (mih) * 4096 + mi * 1024);     \
  } while (0)

#define LDB4(ks)                                                               \
  do {                                                                         \
    _Pragma("unroll") for (int ni = 0; ni < 4; ++ni)                           \
        bv[ni] = *(const s16x8*)((const char*)lds + bufR + rdB +               \
                                 (ks) * 16384 + ni * 1024);                    \
  } while (0)

#define MFMA16(mih)                                                            \
  do {                                                                         \
    _Pragma("unroll") for (int mi = 0; mi < 4; ++mi)                           \
        _Pragma("unroll") for (int ni = 0; ni < 4; ++ni)                       \
            acc[(mih) * 4 + mi][ni] = __builtin_amdgcn_mfma_f32_16x16x32_bf16( \
                av[mi], bv[ni], acc[(mih) * 4 + mi][ni], 0, 0, 0);             \
  } while (0)

#define STAGE(srcbase, bufo, op, h, koff)                                      \
  do {                                                                         \
    __builtin_amdgcn_global_load_lds(                                          \
        AS1((srcbase) + (koff) + (h) * 64),                                    \
        AS3((char*)lds + (bufo) + (op) * 32768 + (h) * 16384 + wv * 1024),     \
        16, 0, 0);                                                             \
    __builtin_amdgcn_global_load_lds(                                          \
        AS1((srcbase) + 128 * Kb + (koff) + (h) * 64),                         \
        AS3((char*)lds + (bufo) + (op) * 32768 + (h) * 16384 + wv * 1024 +     \
            8192),                                                             \
        16, 0, 0);                                                             \
  } while (0)

__global__ void __launch_bounds__(512, 2)
gemm256(const unsigned short* __restrict__ A, const unsigned short* __restrict__ B,
        const float* __restrict__ scale, const float* __restrict__ bias,
        float* __restrict__ C, const int M, const int N, const int K) {
  __shared__ unsigned short lds[65536];  // 128 KiB
  const int tid = threadIdx.x;
  const int lane = tid & 63;
  const int wv = tid >> 6;   // 0..7
  const int wm = wv >> 2;    // 0..1
  const int wn = wv & 3;     // 0..3
  const int lr = lane & 15, lk = lane >> 4;

  // XCD-aware swizzle (bijective: nwg % 8 == 0 for our shape)
  const int mt = M >> 8, nt = N >> 8;
  const int nwg = mt * nt;
  const int orig = blockIdx.x;
  const int wg = (nwg & 7) ? orig : ((orig & 7) * (nwg >> 3) + (orig >> 3));
  const int bm = wg % mt;
  const int bn = wg / mt;
  const int rA0 = bm * 256, rB0 = bn * 256;

  // ds_read per-thread byte bases (swizzled column is per-thread constant)
  const int swc = (lk ^ ((lr >> 1) & 3)) * 16;
  const int rdA = (wm * 128 + lr) * 64 + swc;
  const int rdB = 32768 + (wn * 64 + lr) * 64 + swc;

  // stage per-thread source base (inverse-swizzled)
  const int q = ((wv * 16 + (lane >> 2)) >> 1) & 3;
  const int kc2 = (lane & 3) ^ q;
  const long Kb = (long)K * 2;
  const char* sA0 = (const char*)A + (long)(rA0 + wv * 16 + (lane >> 2)) * Kb + kc2 * 16;
  const char* sB0 = (const char*)B + (long)(rB0 + wv * 16 + (lane >> 2)) * Kb + kc2 * 16;

  f32x4 acc[8][4] = {};
  const int NT = K >> 6;

  // prologue: stage tile 0 into buf0, order [A-K0, B-K0, A-K1, B-K1]
  STAGE(sA0, 0, 0, 0, 0);
  STAGE(sB0, 0, 1, 0, 0);
  STAGE(sA0, 0, 0, 1, 0);
  STAGE(sB0, 0, 1, 1, 0);
  WAITV4();  // K0 halves landed; K1 (4 loads) in flight
  BAR();

  for (int t = 0; t < NT - 1; ++t) {
    const int bufR = (t & 1) * 65536;
    const int bufW = 65536 - bufR;
    const long koff = (long)(t + 1) * 128;
    s16x8 av[4], bv[4];

    // phase 1: ks0, mih0
    LDA4(0, 0); LDB4(0);
    STAGE(sA0, bufW, 0, 0, koff);
    BAR(); LGK0(); SCHED0(); PRIO(1);
    MFMA16(0);
    PRIO(0); BAR();

    // phase 2: ks0, mih1
    LDA4(0, 1);
    STAGE(sB0, bufW, 1, 0, koff);
    BAR(); LGK0(); SCHED0(); PRIO(1);
    MFMA16(1);
    PRIO(0); WAITV4(); BAR();  // K1(t) landed; K0(t+1) in flight

    // phase 3: ks1, mih0
    LDA4(1, 0); LDB4(1);
    STAGE(sA0, bufW, 0, 1, koff);
    BAR(); LGK0(); SCHED0(); PRIO(1);
    MFMA16(0);
    PRIO(0); BAR();

    // phase 4: ks1, mih1
    LDA4(1, 1);
    STAGE(sB0, bufW, 1, 1, koff);
    BAR(); LGK0(); SCHED0(); PRIO(1);
    MFMA16(1);
    PRIO(0); WAITV4(); BAR();  // K0(t+1) landed; K1(t+1) in flight
  }

  // peeled last tile (no stages)
  {
    const int bufR = ((NT - 1) & 1) * 65536;
    s16x8 av[4], bv[4];
    LDA4(0, 0); LDB4(0);
    BAR(); LGK0(); SCHED0(); PRIO(1); MFMA16(0); PRIO(0); BAR();
    LDA4(0, 1);
    BAR(); LGK0(); SCHED0(); PRIO(1); MFMA16(1); PRIO(0); WAITV0(); BAR();
    LDA4(1, 0); LDB4(1);
    BAR(); LGK0(); SCHED0(); PRIO(1); MFMA16(0); PRIO(0); BAR();
    LDA4(1, 1);
    BAR(); LGK0(); SCHED0(); PRIO(1); MFMA16(1); PRIO(0);
  }

  // epilogue: C = acc*scale + bias ; C/D layout: col=lane&15, row=(lane>>4)*4+reg
  const float s = scale[0];
  const int n0 = rB0 + wn * 64 + lr;
  float bb[4];
#pragma unroll
  for (int ni = 0; ni < 4; ++ni) bb[ni] = bias[n0 + ni * 16];
#pragma unroll
  for (int mi = 0; mi < 8; ++mi) {
#pragma unroll
    for (int rg = 0; rg < 4; ++rg) {
      float* crow = C + (size_t)(rA0 + wm * 128 + mi * 16 + lk * 4 + rg) * N + n0;
#pragma unroll
      for (int ni = 0; ni < 4; ++ni)
        crow[ni * 16] = acc[mi][ni][rg] * s + bb[ni];
    }
  }
}

// ---------------- round-1 128x128 kernel kept as fallback ----------------
template <bool ABF, bool BBF>
__global__ void __launch_bounds__(256, 2)
gemm_bin(const void* __restrict__ Ap, const void* __restrict__ Bp,
         const float* __restrict__ scale, const float* __restrict__ bias,
         float* __restrict__ C, const int M, const int N, const int K) {
  __shared__ unsigned short As[128 * 64];
  __shared__ unsigned short Bs[128 * 64];
  const int tid = threadIdx.x;
  const int lane = tid & 63;
  const int wv = tid >> 6;
  const int wm = wv >> 1, wn = wv & 1;
  const int bn = blockIdx.x, bm = blockIdx.y;
  const int lr = lane & 15, lk = lane >> 4;
  f32x4 acc[4][4] = {};
  const int rA0 = bm * 128, rB0 = bn * 128;

  for (int k0 = 0; k0 < K; k0 += 64) {
    if constexpr (ABF) {
      const unsigned short* Ag = (const unsigned short*)Ap;
#pragma unroll
      for (int i = 0; i < 4; ++i) {
        const int cbase = i * 256 + wv * 64;
        const int c = cbase + lane;
        const int row = c >> 3, kc = c & 7;
        const int kcs = kc ^ (row & 7);
        const unsigned short* src = Ag + (size_t)(rA0 + row) * K + (k0 + kcs * 8);
        __builtin_amdgcn_global_load_lds(AS1(src), AS3(&As[cbase * 8]), 16, 0, 0);
      }
    } else {
      const float* Ag = (const float*)Ap;
#pragma unroll
      for (int i = 0; i < 4; ++i) {
        const int c = i * 256 + tid;
        const int row = c >> 3, kc = c & 7;
        const f32x4* src = (const f32x4*)(Ag + (size_t)(rA0 + row) * K + (k0 + kc * 8));
        f32x4 v0 = src[0], v1 = src[1];
        s16x8 o;
        o[0] = (short)f2bf(v0[0]); o[1] = (short)f2bf(v0[1]);
        o[2] = (short)f2bf(v0[2]); o[3] = (short)f2bf(v0[3]);
        o[4] = (short)f2bf(v1[0]); o[5] = (short)f2bf(v1[1]);
        o[6] = (short)f2bf(v1[2]); o[7] = (short)f2bf(v1[3]);
        *(s16x8*)&As[(row * 8 + (kc ^ (row & 7))) * 8] = o;
      }
    }
    if constexpr (BBF) {
      const unsigned short* Bg = (const unsigned short*)Bp;
#pragma unroll
      for (int i = 0; i < 4; ++i) {
        const int cbase = i * 256 + wv * 64;
        const int c = cbase + lane;
        const int row = c >> 3, kc = c & 7;
        const int kcs = kc ^ (row & 7);
        const unsigned short* src = Bg + (size_t)(rB0 + row) * K + (k0 + kcs * 8);
        __builtin_amdgcn_global_load_lds(AS1(src), AS3(&Bs[cbase * 8]), 16, 0, 0);
      }
    } else {
      const unsigned int* Bg = (const unsigned int*)Bp;
#pragma unroll
      for (int i = 0; i < 4; ++i) {
        const int c = i * 256 + tid;
        const int row = c >> 3, kc = c & 7;
        const u32x4* src = (const u32x4*)(Bg + (size_t)(rB0 + row) * K + (k0 + kc * 8));
        u32x4 v0 = src[0], v1 = src[1];
        s16x8 o;
        o[0] = (short)(0x3F80u | ((v0[0] >> 16) & 0x8000u));
        o[1] = (short)(0x3F80u | ((v0[1] >> 16) & 0x8000u));
        o[2] = (short)(0x3F80u | ((v0[2] >> 16) & 0x8000u));
        o[3] = (short)(0x3F80u | ((v0[3] >> 16) & 0x8000u));
        o[4] = (short)(0x3F80u | ((v1[0] >> 16) & 0x8000u));
        o[5] = (short)(0x3F80u | ((v1[1] >> 16) & 0x8000u));
        o[6] = (short)(0x3F80u | ((v1[2] >> 16) & 0x8000u));
        o[7] = (short)(0x3F80u | ((v1[3] >> 16) & 0x8000u));
        *(s16x8*)&Bs[(row * 8 + (kc ^ (row & 7))) * 8] = o;
      }
    }
    __syncthreads();
#pragma unroll
    for (int ks = 0; ks < 2; ++ks) {
      s16x8 a[4], b[4];
#pragma unroll
      for (int mi = 0; mi < 4; ++mi) {
        const int row = wm * 64 + mi * 16 + lr;
        const int kc = ks * 4 + lk;
        a[mi] = *(const s16x8*)&As[(row * 8 + (kc ^ (row & 7))) * 8];
      }
#pragma unroll
      for (int ni = 0; ni < 4; ++ni) {
        const int row = wn * 64 + ni * 16 + lr;
        const int kc = ks * 4 + lk;
        b[ni] = *(const s16x8*)&Bs[(row * 8 + (kc ^ (row & 7))) * 8];
      }
#pragma unroll
      for (int mi = 0; mi < 4; ++mi)
#pragma unroll
        for (int ni = 0; ni < 4; ++ni)
          acc[mi][ni] = __builtin_amdgcn_mfma_f32_16x16x32_bf16(a[mi], b[ni],
                                                               acc[mi][ni], 0, 0, 0);
    }
    __syncthreads();
  }

  const float s = scale[0];
  const int n0 = rB0 + wn * 64 + lr;
  const int m0 = rA0 + wm * 64 + lk * 4;
  float bb[4];
#pragma unroll
  for (int ni = 0; ni < 4; ++ni) bb[ni] = bias[n0 + ni * 16];
#pragma unroll
  for (int mi = 0; mi < 4; ++mi) {
#pragma unroll
    for (int r = 0; r < 4; ++r) {
      float* crow = C + (size_t)(m0 + mi * 16 + r) * N + n0;
#pragma unroll
      for (int ni = 0; ni < 4; ++ni)
        crow[ni * 16] = acc[mi][ni][r] * s + bb[ni];
    }
  }
}

extern "C" void kernel_launch(void* const* d_in, const int* in_sizes, int n_in,
                              void* d_out, int out_size, void* d_ws, size_t ws_size,
                              hipStream_t stream) {
  const float* x = (const float*)d_in[0];
  const float* w = (const float*)d_in[1];
  const float* scale = (const float*)d_in[2];
  const float* bias = (const float*)d_in[3];
  float* out = (float*)d_out;

  const int K = 4096;
  const int M = in_sizes[0] / K;  // 8192
  const int N = in_sizes[3];      // 16384

  const size_t needA = (size_t)M * K * sizeof(unsigned short);
  const size_t needB = (size_t)N * K * sizeof(unsigned short);

  if (ws_size >= needA + needB && (M % 256) == 0 && (N % 256) == 0) {
    unsigned short* xb = (unsigned short*)d_ws;
    unsigned short* wb = (unsigned short*)((char*)d_ws + needA);
    cvt_f32_bf16<<<2048, 256, 0, stream>>>(x, xb, (M * K) / 8);
    bin_f32_bf16<<<2048, 256, 0, stream>>>((const unsigned int*)w, wb, (N * K) / 8);
    gemm256<<<dim3((M / 256) * (N / 256)), 512, 0, stream>>>(xb, wb, scale, bias,
                                                             out, M, N, K);
  } else if (ws_size >= needA + needB) {
    unsigned short* xb = (unsigned short*)d_ws;
    unsigned short* wb = (unsigned short*)((char*)d_ws + needA);
    cvt_f32_bf16<<<2048, 256, 0, stream>>>(x, xb, (M * K) / 8);
    bin_f32_bf16<<<2048, 256, 0, stream>>>((const unsigned int*)w, wb, (N * K) / 8);
    gemm_bin<true, true><<<dim3(N / 128, M / 128), 256, 0, stream>>>(
        xb, wb, scale, bias, out, M, N, K);
  } else if (ws_size >= needB) {
    unsigned short* wb = (unsigned short*)d_ws;
    bin_f32_bf16<<<2048, 256, 0, stream>>>((const unsigned int*)w, wb, (N * K) / 8);
    gemm_bin<false, true><<<dim3(N / 128, M / 128), 256, 0, stream>>>(
        x, wb, scale, bias, out, M, N, K);
  } else {
    gemm_bin<false, false><<<dim3(N / 128, M / 128), 256, 0, stream>>>(
        x, w, scale, bias, out, M, N, K);
  }
}

// Round 3
// 1272.812 us; speedup vs baseline: 1.0805x; 1.0280x over previous
//
#include <hip/hip_runtime.h>
#include <hip/hip_bf16.h>

// BinaryLinear: C[M,N] = (x[M,K] @ sign(W)[N,K]^T) * scale + bias
// M=8192 K=4096 N=16384 fp32. Binarize W -> +-1 bf16, round x -> bf16,
// bf16 MFMA GEMM. Round 3: 256x256 8-wave, TWO barriers per K-tile
// (publication barrier per K-half), 12 ds_reads issued ahead of 32-MFMA
// cluster (compiler emits counted lgkmcnt), counted vmcnt(4) never 0.

typedef __attribute__((ext_vector_type(4))) float f32x4;
typedef __attribute__((ext_vector_type(8))) short s16x8;
typedef __attribute__((ext_vector_type(4))) unsigned int u32x4;

#define AS1(p) ((const __attribute__((address_space(1))) void*)(p))
#define AS3(p) ((__attribute__((address_space(3))) void*)(p))

__device__ __forceinline__ unsigned short f2bf(float f) {
  unsigned u = __float_as_uint(f);
  u += 0x7FFFu + ((u >> 16) & 1u);
  return (unsigned short)(u >> 16);
}

__global__ void __launch_bounds__(256) cvt_f32_bf16(const float* __restrict__ in,
                                                    unsigned short* __restrict__ out,
                                                    int n8) {
  int i = blockIdx.x * 256 + threadIdx.x;
  const int stride = gridDim.x * 256;
  for (; i < n8; i += stride) {
    const f32x4* p = (const f32x4*)in + (size_t)i * 2;
    f32x4 v0 = p[0], v1 = p[1];
    s16x8 o;
    o[0] = (short)f2bf(v0[0]); o[1] = (short)f2bf(v0[1]);
    o[2] = (short)f2bf(v0[2]); o[3] = (short)f2bf(v0[3]);
    o[4] = (short)f2bf(v1[0]); o[5] = (short)f2bf(v1[1]);
    o[6] = (short)f2bf(v1[2]); o[7] = (short)f2bf(v1[3]);
    *(s16x8*)(out + (size_t)i * 8) = o;
  }
}

__global__ void __launch_bounds__(256) bin_f32_bf16(const unsigned int* __restrict__ in,
                                                    unsigned short* __restrict__ out,
                                                    int n8) {
  int i = blockIdx.x * 256 + threadIdx.x;
  const int stride = gridDim.x * 256;
  for (; i < n8; i += stride) {
    const u32x4* p = (const u32x4*)in + (size_t)i * 2;
    u32x4 v0 = p[0], v1 = p[1];
    s16x8 o;  // bf16 +-1.0 from fp32 sign bit
    o[0] = (short)(0x3F80u | ((v0[0] >> 16) & 0x8000u));
    o[1] = (short)(0x3F80u | ((v0[1] >> 16) & 0x8000u));
    o[2] = (short)(0x3F80u | ((v0[2] >> 16) & 0x8000u));
    o[3] = (short)(0x3F80u | ((v0[3] >> 16) & 0x8000u));
    o[4] = (short)(0x3F80u | ((v1[0] >> 16) & 0x8000u));
    o[5] = (short)(0x3F80u | ((v1[1] >> 16) & 0x8000u));
    o[6] = (short)(0x3F80u | ((v1[2] >> 16) & 0x8000u));
    o[7] = (short)(0x3F80u | ((v1[3] >> 16) & 0x8000u));
    *(s16x8*)(out + (size_t)i * 8) = o;
  }
}

// ---------------------------------------------------------------------------
// 256x256 tile, BK=64, 512 threads = 8 waves (2M x 4N), wave tile 128x64.
// LDS (128 KiB): buf{0,1} x op{A,B} x Khalf{0,1} regions of 256 rows x 64 B.
//   byte = buf*65536 + op*32768 + h*16384 + row*64 + (kc ^ ((row>>1)&3))*16
// Stage: global_load_lds w=16, linear dest, inverse-swizzled source (rule #21).
// Per K-half sub-step: [stage next-tile half (4 loads)] [12 ds_read_b128]
// [32 MFMA] [vmcnt(4)] [barrier]. Two barriers per K-tile. Compiler inserts
// counted lgkmcnt between reads and MFMA; 4 prefetched reads complete under
// the first 16-MFMA cluster. Each inter-asm region holds exactly one 4-load
// stage group -> vmcnt(4) retirement order is exact.
// ---------------------------------------------------------------------------

#define WAITV4() asm volatile("s_waitcnt vmcnt(4)" ::: "memory")
#define WAITV0() asm volatile("s_waitcnt vmcnt(0)" ::: "memory")
#define BAR()    __builtin_amdgcn_s_barrier()
#define SCHED0() __builtin_amdgcn_sched_barrier(0)
#define PRIO(x)  __builtin_amdgcn_s_setprio(x)

#define LDSB ((const char*)lds)

#define LOADSUB(ks)                                                            \
  do {                                                                         \
    _Pragma("unroll") for (int mi = 0; mi < 4; ++mi)                           \
        a0[mi] = *(const s16x8*)(LDSB + bufR + rdA + (ks) * 16384 + mi * 1024);\
    _Pragma("unroll") for (int ni = 0; ni < 4; ++ni)                           \
        b0[ni] = *(const s16x8*)(LDSB + bufR + rdB + (ks) * 16384 + ni * 1024);\
    _Pragma("unroll") for (int mi = 0; mi < 4; ++mi)                           \
        a1[mi] = *(const s16x8*)(LDSB + bufR + rdA + (ks) * 16384 + 4096 +     \
                                 mi * 1024);                                   \
  } while (0)

#define MFMA32()                                                               \
  do {                                                                         \
    _Pragma("unroll") for (int mi = 0; mi < 4; ++mi)                           \
        _Pragma("unroll") for (int ni = 0; ni < 4; ++ni)                       \
            acc[mi][ni] = __builtin_amdgcn_mfma_f32_16x16x32_bf16(             \
                a0[mi], b0[ni], acc[mi][ni], 0, 0, 0);                         \
    _Pragma("unroll") for (int mi = 0; mi < 4; ++mi)                           \
        _Pragma("unroll") for (int ni = 0; ni < 4; ++ni)                       \
            acc[4 + mi][ni] = __builtin_amdgcn_mfma_f32_16x16x32_bf16(         \
                a1[mi], b0[ni], acc[4 + mi][ni], 0, 0, 0);                     \
  } while (0)

#define STAGE(srcbase, bufo, op, h, koff)                                      \
  do {                                                                         \
    __builtin_amdgcn_global_load_lds(                                          \
        AS1((srcbase) + (koff) + (h) * 64),                                    \
        AS3((char*)lds + (bufo) + (op) * 32768 + (h) * 16384 + wv * 1024),     \
        16, 0, 0);                                                             \
    __builtin_amdgcn_global_load_lds(                                          \
        AS1((srcbase) + 128 * Kb + (koff) + (h) * 64),                         \
        AS3((char*)lds + (bufo) + (op) * 32768 + (h) * 16384 + wv * 1024 +     \
            8192),                                                             \
        16, 0, 0);                                                             \
  } while (0)

__global__ void __launch_bounds__(512, 2)
gemm256(const unsigned short* __restrict__ A, const unsigned short* __restrict__ B,
        const float* __restrict__ scale, const float* __restrict__ bias,
        float* __restrict__ C, const int M, const int N, const int K) {
  __shared__ unsigned short lds[65536];  // 128 KiB
  const int tid = threadIdx.x;
  const int lane = tid & 63;
  const int wv = tid >> 6;   // 0..7
  const int wm = wv >> 2;    // 0..1
  const int wn = wv & 3;     // 0..3
  const int lr = lane & 15, lk = lane >> 4;

  // XCD-aware swizzle (bijective: nwg % 8 == 0 for our shape)
  const int mt = M >> 8, nt = N >> 8;
  const int nwg = mt * nt;
  const int orig = blockIdx.x;
  const int wg = (nwg & 7) ? orig : ((orig & 7) * (nwg >> 3) + (orig >> 3));
  const int bm = wg % mt;
  const int bn = wg / mt;
  const int rA0 = bm * 256, rB0 = bn * 256;

  // ds_read per-thread byte bases (swizzled column is per-thread constant)
  const int swc = (lk ^ ((lr >> 1) & 3)) * 16;
  const int rdA = (wm * 128 + lr) * 64 + swc;
  const int rdB = 32768 + (wn * 64 + lr) * 64 + swc;

  // stage per-thread source base (inverse-swizzled)
  const int q = ((wv * 16 + (lane >> 2)) >> 1) & 3;
  const int kc2 = (lane & 3) ^ q;
  const long Kb = (long)K * 2;
  const char* sA0 = (const char*)A + (long)(rA0 + wv * 16 + (lane >> 2)) * Kb + kc2 * 16;
  const char* sB0 = (const char*)B + (long)(rB0 + wv * 16 + (lane >> 2)) * Kb + kc2 * 16;

  f32x4 acc[8][4] = {};
  const int NT = K >> 6;

  // prologue: stage tile 0 into buf0, groups [A-K0,B-K0] then [A-K1,B-K1]
  STAGE(sA0, 0, 0, 0, 0);
  STAGE(sB0, 0, 1, 0, 0);
  WAITV4();  // no-op spacing: 4 outstanding
  STAGE(sA0, 0, 0, 1, 0);
  STAGE(sB0, 0, 1, 1, 0);
  WAITV4();  // K0(0) landed; K1(0) 4 loads in flight
  BAR(); SCHED0();

  for (int t = 0; t < NT - 1; ++t) {
    const int bufR = (t & 1) * 65536;
    const int bufW = 65536 - bufR;
    const long koff = (long)(t + 1) * 128;
    {  // ---- sub-step ks=0: reads buf[t].K0 (published), stages K0(t+1) ----
      s16x8 a0[4], b0[4], a1[4];
      STAGE(sA0, bufW, 0, 0, koff);
      STAGE(sB0, bufW, 1, 0, koff);
      LOADSUB(0);
      PRIO(1);
      MFMA32();
      PRIO(0);
      WAITV4();  // retire K1(t) [staged prev tile]; keep K0(t+1) in flight
      BAR(); SCHED0();  // publish K1(t)
    }
    {  // ---- sub-step ks=1: reads buf[t].K1, stages K1(t+1) ----
      s16x8 a0[4], b0[4], a1[4];
      STAGE(sA0, bufW, 0, 1, koff);
      STAGE(sB0, bufW, 1, 1, koff);
      LOADSUB(1);
      PRIO(1);
      MFMA32();
      PRIO(0);
      WAITV4();  // retire K0(t+1); keep K1(t+1) in flight
      BAR(); SCHED0();  // publish K0(t+1)
    }
  }

  // peeled last tile (no stages)
  {
    const int bufR = ((NT - 1) & 1) * 65536;
    {
      s16x8 a0[4], b0[4], a1[4];
      LOADSUB(0);
      PRIO(1); MFMA32(); PRIO(0);
      WAITV0();  // K1(NT-1) landed
      BAR(); SCHED0();
    }
    {
      s16x8 a0[4], b0[4], a1[4];
      LOADSUB(1);
      PRIO(1); MFMA32(); PRIO(0);
    }
  }

  // epilogue: C = acc*scale + bias ; C/D layout: col=lane&15, row=(lane>>4)*4+reg
  const float s = scale[0];
  const int n0 = rB0 + wn * 64 + lr;
  float bb[4];
#pragma unroll
  for (int ni = 0; ni < 4; ++ni) bb[ni] = bias[n0 + ni * 16];
#pragma unroll
  for (int mi = 0; mi < 8; ++mi) {
#pragma unroll
    for (int rg = 0; rg < 4; ++rg) {
      float* crow = C + (size_t)(rA0 + wm * 128 + mi * 16 + lk * 4 + rg) * N + n0;
#pragma unroll
      for (int ni = 0; ni < 4; ++ni)
        crow[ni * 16] = acc[mi][ni][rg] * s + bb[ni];
    }
  }
}

// ---------------- round-1 128x128 kernel kept as fallback ----------------
template <bool ABF, bool BBF>
__global__ void __launch_bounds__(256, 2)
gemm_bin(const void* __restrict__ Ap, const void* __restrict__ Bp,
         const float* __restrict__ scale, const float* __restrict__ bias,
         float* __restrict__ C, const int M, const int N, const int K) {
  __shared__ unsigned short As[128 * 64];
  __shared__ unsigned short Bs[128 * 64];
  const int tid = threadIdx.x;
  const int lane = tid & 63;
  const int wv = tid >> 6;
  const int wm = wv >> 1, wn = wv & 1;
  const int bn = blockIdx.x, bm = blockIdx.y;
  const int lr = lane & 15, lk = lane >> 4;
  f32x4 acc[4][4] = {};
  const int rA0 = bm * 128, rB0 = bn * 128;

  for (int k0 = 0; k0 < K; k0 += 64) {
    if constexpr (ABF) {
      const unsigned short* Ag = (const unsigned short*)Ap;
#pragma unroll
      for (int i = 0; i < 4; ++i) {
        const int cbase = i * 256 + wv * 64;
        const int c = cbase + lane;
        const int row = c >> 3, kc = c & 7;
        const int kcs = kc ^ (row & 7);
        const unsigned short* src = Ag + (size_t)(rA0 + row) * K + (k0 + kcs * 8);
        __builtin_amdgcn_global_load_lds(AS1(src), AS3(&As[cbase * 8]), 16, 0, 0);
      }
    } else {
      const float* Ag = (const float*)Ap;
#pragma unroll
      for (int i = 0; i < 4; ++i) {
        const int c = i * 256 + tid;
        const int row = c >> 3, kc = c & 7;
        const f32x4* src = (const f32x4*)(Ag + (size_t)(rA0 + row) * K + (k0 + kc * 8));
        f32x4 v0 = src[0], v1 = src[1];
        s16x8 o;
        o[0] = (short)f2bf(v0[0]); o[1] = (short)f2bf(v0[1]);
        o[2] = (short)f2bf(v0[2]); o[3] = (short)f2bf(v0[3]);
        o[4] = (short)f2bf(v1[0]); o[5] = (short)f2bf(v1[1]);
        o[6] = (short)f2bf(v1[2]); o[7] = (short)f2bf(v1[3]);
        *(s16x8*)&As[(row * 8 + (kc ^ (row & 7))) * 8] = o;
      }
    }
    if constexpr (BBF) {
      const unsigned short* Bg = (const unsigned short*)Bp;
#pragma unroll
      for (int i = 0; i < 4; ++i) {
        const int cbase = i * 256 + wv * 64;
        const int c = cbase + lane;
        const int row = c >> 3, kc = c & 7;
        const int kcs = kc ^ (row & 7);
        const unsigned short* src = Bg + (size_t)(rB0 + row) * K + (k0 + kcs * 8);
        __builtin_amdgcn_global_load_lds(AS1(src), AS3(&Bs[cbase * 8]), 16, 0, 0);
      }
    } else {
      const unsigned int* Bg = (const unsigned int*)Bp;
#pragma unroll
      for (int i = 0; i < 4; ++i) {
        const int c = i * 256 + tid;
        const int row = c >> 3, kc = c & 7;
        const u32x4* src = (const u32x4*)(Bg + (size_t)(rB0 + row) * K + (k0 + kc * 8));
        u32x4 v0 = src[0], v1 = src[1];
        s16x8 o;
        o[0] = (short)(0x3F80u | ((v0[0] >> 16) & 0x8000u));
        o[1] = (short)(0x3F80u | ((v0[1] >> 16) & 0x8000u));
        o[2] = (short)(0x3F80u | ((v0[2] >> 16) & 0x8000u));
        o[3] = (short)(0x3F80u | ((v0[3] >> 16) & 0x8000u));
        o[4] = (short)(0x3F80u | ((v1[0] >> 16) & 0x8000u));
        o[5] = (short)(0x3F80u | ((v1[1] >> 16) & 0x8000u));
        o[6] = (short)(0x3F80u | ((v1[2] >> 16) & 0x8000u));
        o[7] = (short)(0x3F80u | ((v1[3] >> 16) & 0x8000u));
        *(s16x8*)&Bs[(row * 8 + (kc ^ (row & 7))) * 8] = o;
      }
    }
    __syncthreads();
#pragma unroll
    for (int ks = 0; ks < 2; ++ks) {
      s16x8 a[4], b[4];
#pragma unroll
      for (int mi = 0; mi < 4; ++mi) {
        const int row = wm * 64 + mi * 16 + lr;
        const int kc = ks * 4 + lk;
        a[mi] = *(const s16x8*)&As[(row * 8 + (kc ^ (row & 7))) * 8];
      }
#pragma unroll
      for (int ni = 0; ni < 4; ++ni) {
        const int row = wn * 64 + ni * 16 + lr;
        const int kc = ks * 4 + lk;
        b[ni] = *(const s16x8*)&Bs[(row * 8 + (kc ^ (row & 7))) * 8];
      }
#pragma unroll
      for (int mi = 0; mi < 4; ++mi)
#pragma unroll
        for (int ni = 0; ni < 4; ++ni)
          acc[mi][ni] = __builtin_amdgcn_mfma_f32_16x16x32_bf16(a[mi], b[ni],
                                                               acc[mi][ni], 0, 0, 0);
    }
    __syncthreads();
  }

  const float s = scale[0];
  const int n0 = rB0 + wn * 64 + lr;
  const int m0 = rA0 + wm * 64 + lk * 4;
  float bb[4];
#pragma unroll
  for (int ni = 0; ni < 4; ++ni) bb[ni] = bias[n0 + ni * 16];
#pragma unroll
  for (int mi = 0; mi < 4; ++mi) {
#pragma unroll
    for (int r = 0; r < 4; ++r) {
      float* crow = C + (size_t)(m0 + mi * 16 + r) * N + n0;
#pragma unroll
      for (int ni = 0; ni < 4; ++ni)
        crow[ni * 16] = acc[mi][ni][r] * s + bb[ni];
    }
  }
}

extern "C" void kernel_launch(void* const* d_in, const int* in_sizes, int n_in,
                              void* d_out, int out_size, void* d_ws, size_t ws_size,
                              hipStream_t stream) {
  const float* x = (const float*)d_in[0];
  const float* w = (const float*)d_in[1];
  const float* scale = (const float*)d_in[2];
  const float* bias = (const float*)d_in[3];
  float* out = (float*)d_out;

  const int K = 4096;
  const int M = in_sizes[0] / K;  // 8192
  const int N = in_sizes[3];      // 16384

  const size_t needA = (size_t)M * K * sizeof(unsigned short);
  const size_t needB = (size_t)N * K * sizeof(unsigned short);

  if (ws_size >= needA + needB && (M % 256) == 0 && (N % 256) == 0) {
    unsigned short* xb = (unsigned short*)d_ws;
    unsigned short* wb = (unsigned short*)((char*)d_ws + needA);
    cvt_f32_bf16<<<2048, 256, 0, stream>>>(x, xb, (M * K) / 8);
    bin_f32_bf16<<<2048, 256, 0, stream>>>((const unsigned int*)w, wb, (N * K) / 8);
    gemm256<<<dim3((M / 256) * (N / 256)), 512, 0, stream>>>(xb, wb, scale, bias,
                                                             out, M, N, K);
  } else if (ws_size >= needA + needB) {
    unsigned short* xb = (unsigned short*)d_ws;
    unsigned short* wb = (unsigned short*)((char*)d_ws + needA);
    cvt_f32_bf16<<<2048, 256, 0, stream>>>(x, xb, (M * K) / 8);
    bin_f32_bf16<<<2048, 256, 0, stream>>>((const unsigned int*)w, wb, (N * K) / 8);
    gemm_bin<true, true><<<dim3(N / 128, M / 128), 256, 0, stream>>>(
        xb, wb, scale, bias, out, M, N, K);
  } else if (ws_size >= needB) {
    unsigned short* wb = (unsigned short*)d_ws;
    bin_f32_bf16<<<2048, 256, 0, stream>>>((const unsigned int*)w, wb, (N * K) / 8);
    gemm_bin<false, true><<<dim3(N / 128, M / 128), 256, 0, stream>>>(
        x, wb, scale, bias, out, M, N, K);
  } else {
    gemm_bin<false, false><<<dim3(N / 128, M / 128), 256, 0, stream>>>(
        x, w, scale, bias, out, M, N, K);
  }
}